// Round 14
// baseline (2581.801 us; speedup 1.0000x reference)
//
#include <hip/hip_runtime.h>
#include <hip/hip_bf16.h>
#include <stdint.h>

// Problem constants
#define S_LEN 256
#define BATCH 64
#define HID   1024
#define RDIM  512
#define VOC   512
#define GATES 4096  // 4*HID

// d_out element offsets (fp32): logits [S][B][V], h [1][B][H], c [1][B][H], loss [1]
#define OFF_H    8388608u
#define OFF_C    8454144u
#define OFF_LOSS 8519680u

typedef __attribute__((ext_vector_type(8))) short short8;   // 8 x bf16 (4 VGPR)
typedef __attribute__((ext_vector_type(4))) float f32x4;
typedef __attribute__((ext_vector_type(4))) int   i32x4;
typedef unsigned long long u64;

#define HBUF_BYTES (128u * 1024u)  // one h fragment buffer: 4bt*32kk*64lane*16B

// ---------------- helpers ----------------

__device__ inline unsigned short f2bf(float f) {
  unsigned u = __builtin_bit_cast(unsigned, f);
  return (unsigned short)((u + 0x7FFFu + ((u >> 16) & 1u)) >> 16);
}

__device__ inline u64 pack4(float a, float b, float c, float d) {
  return (u64)f2bf(a) | ((u64)f2bf(b) << 16) | ((u64)f2bf(c) << 32) | ((u64)f2bf(d) << 48);
}

__device__ inline f32x4 mfma16(short8 a, short8 b, f32x4 c) {
  return __builtin_amdgcn_mfma_f32_16x16x32_bf16(a, b, c, 0, 0, 0);
}

__device__ inline void stfrag8(char* p, u64 v) {
  __hip_atomic_store((u64*)p, v, __ATOMIC_RELAXED, __HIP_MEMORY_SCOPE_AGENT);
}

// ring byte offset of h element block (b, hcol..hcol+3), hcol % 4 == 0
// (B-operand fragment layout: lane = (b&15) + k-chunk*16, 8 bf16 per lane entry)
__device__ inline size_t fragoff(int b, int hcol) {
  int bt = b >> 4, kk = hcol >> 5;
  int lane = (b & 15) + (((hcol >> 3) & 3) << 4);
  return ((((size_t)bt * 32 + kk) * 64 + lane) << 4) + (size_t)((hcol & 7) * 2);
}

__device__ inline float sigm(float x) {
  return __builtin_amdgcn_rcpf(1.f + __expf(-x));
}
__device__ inline float tanh_(float x) {
  return 1.f - 2.f * __builtin_amdgcn_rcpf(__expf(2.f * x) + 1.f);
}

// ---------------- prep: T table, fc_w->bf16, zero flags/loss ----------------
// grid 517 x 256
__global__ void __launch_bounds__(256) k_prep(
    const float* __restrict__ W_ih, const float* __restrict__ b_ih,
    const float* __restrict__ b_hh, const float* __restrict__ fc_w,
    float* __restrict__ T, unsigned short* __restrict__ fcw_bf,
    unsigned* __restrict__ flags, float* __restrict__ loss_slot)
{
  __shared__ float stage[64][65];
  const int bid = blockIdx.x, tid = threadIdx.x;
  if (bid < 512) {
    // T[e][c] = W_ih[c][e] + b_ih[c] + b_hh[c]  (64x64 transpose tile)
    const int c0 = (bid >> 3) * 64, e0 = (bid & 7) * 64;
    for (int idx = tid; idx < 4096; idx += 256) {
      int i = idx >> 6, jj = idx & 63;
      stage[i][jj] = W_ih[(size_t)(c0 + i) * RDIM + e0 + jj];
    }
    __syncthreads();
    for (int idx = tid; idx < 4096; idx += 256) {
      int jj = idx >> 6, i = idx & 63;
      int c = c0 + i;
      T[(size_t)(e0 + jj) * GATES + c] = stage[i][jj] + b_ih[c] + b_hh[c];
    }
  } else if (bid < 516) {
    // fc_w fp32 -> bf16
    const size_t off = (size_t)(bid - 512) * 131072;
    for (int k = tid; k < 32768; k += 256) {
      float4 v = *(const float4*)(fc_w + off + (size_t)k * 4);
      ushort4 o;
      o.x = f2bf(v.x); o.y = f2bf(v.y); o.z = f2bf(v.z); o.w = f2bf(v.w);
      *(ushort4*)(fcw_bf + off + (size_t)k * 4) = o;
    }
  } else {
    // zero flags (write-through to LLC) + loss accumulator
    for (int k = tid; k < 65536; k += 256)
      __hip_atomic_store(flags + k, 0u, __ATOMIC_RELAXED, __HIP_MEMORY_SCOPE_AGENT);
    if (tid == 0) loss_slot[0] = 0.f;
  }
}

// ---------------- persistent LSTM recurrence ----------------
// R10 data path (best measured: 1310us) with the rendezvous dissolved.
// 64 blocks x 4 waves; block j owns gate cols [16j,16j+16) x 4 gates, W
// slice in LDS; swapped-operand MFMA (cell inputs = own acc regs); 32-frag
// sc0sc1 asm burst with counted vmcnt(24/16/8/0) drains.
// NEW: (block, wave) = independent agent. Consumer wave w's fragment kk
// needs ONLY wave w's slice of source blocks {2kk, 2kk+1}, so sync is a
// per-wave byte flag flags[t][j].byte[w]. NO __syncthreads in the step
// loop (waves decouple across steps; jitter stops accumulating), and the
// burst is GATED PER 8-FRAGMENT CHUNK: chunk c issues as soon as source
// blocks [16c,16c+16) report ready (ballot of per-lane byte polls) --
// chunk loads fly while later chunks are still being polled.
// WAR (2-slot ring) is inductive: flags[t][i].byte_w implies block i wave
// w read ALL of slot (t-1)&1 (it needed every fragment to compute h^t);
// the writer observes those flags during step t before overwriting.
__global__ void __launch_bounds__(256, 1) k_recur(
    const float* __restrict__ W_hh, const float* __restrict__ Tt,
    const int* __restrict__ e_input, const float* __restrict__ emb,
    const int* __restrict__ cond, const float* __restrict__ d_input,
    const int* __restrict__ tf_ptr, const float* __restrict__ W_ih,
    const float* __restrict__ b_ih, const float* __restrict__ b_hh,
    char* __restrict__ hbuf, unsigned* __restrict__ flags,
    unsigned short* __restrict__ outs_r, float* __restrict__ dout)
{
  extern __shared__ char smem[];
  char* Wlds = smem;                         // 128 KiB W fragments (A-operand)
  const int j = blockIdx.x;
  const int tid = threadIdx.x;
  const int w = tid >> 6, l = tid & 63;
  const int tf = tf_ptr[0];

  // ---- pack W_hh slice into LDS fragments (lane = gatecol&15 + kchunk*16) ----
  {
    const int nl = tid >> 2;        // local gate col 0..63 (gate = nl>>4)
    const int kq = tid & 3;
    const int g = nl >> 4, hc = nl & 15;
    const float* wrow = W_hh + (size_t)(g * HID + j * 16 + hc) * HID + kq * 256;
    for (int k8 = 0; k8 < 32; ++k8) {
      const int k = kq * 256 + k8 * 8;
      float4 va = *(const float4*)(wrow + k8 * 8);
      float4 vb = *(const float4*)(wrow + k8 * 8 + 4);
      u64 lo = pack4(va.x, va.y, va.z, va.w);
      u64 hi = pack4(vb.x, vb.y, vb.z, vb.w);
      const int kk = k >> 5;
      const int lane = (nl & 15) + (((k >> 3) & 3) << 4);
      char* p = Wlds + (((size_t)(g * 32 + kk) * 64 + lane) << 4);
      *(u64*)p = lo;
      *(u64*)(p + 8) = hi;
    }
  }

  // ---- cell ownership: b = w*16 + (l&15), hcl = (l>>4)*4 (matches C frag) ----
  const int b = w * 16 + (l & 15);
  const int hcl = (l >> 4) * 4;
  const int hcol = j * 16 + hcl;
  float cr[4];
  {
    const int cd = cond[b];
    float4 h0 = *(const float4*)(emb + (size_t)cd * HID + hcol);
    cr[0] = h0.x; cr[1] = h0.y; cr[2] = h0.z; cr[3] = h0.w;
    stfrag8(hbuf + fragoff(b, hcol), pack4(h0.x, h0.y, h0.z, h0.w));
  }
  // per-wave drain then publish this wave's t=0 byte
  asm volatile("s_waitcnt vmcnt(0)" ::: "memory");
  if (l == 0)
    __hip_atomic_store((unsigned char*)(flags + j) + w, (unsigned char)1,
                       __ATOMIC_RELAXED, __HIP_MEMORY_SCOPE_AGENT);
  __syncthreads();   // Wlds pack visible to all waves (startup only)

#define ISSUE(c)                                                              \
  _Pragma("unroll")                                                           \
  for (int q = 0; q < 8; ++q)                                                 \
    asm volatile("global_load_dwordx4 %0, %1, off sc0 sc1"                    \
                 : "=v"(a[(c) * 8 + q])                                       \
                 : "v"(hbl + (size_t)((c) * 8 + q) * 1024));

#define MFMA_BT(bt)                                                           \
  _Pragma("unroll")                                                           \
  for (int kkl = 0; kkl < 8; ++kkl) {                                         \
    const int kk = (bt) * 8 + kkl;                                            \
    _Pragma("unroll")                                                         \
    for (int nt = 0; nt < 4; ++nt) {                                          \
      short8 Wv = *(const short8*)(Wlds + ((((size_t)nt * 32 + kk) * 64 + l) << 4)); \
      acc[nt] = mfma16(Wv, __builtin_bit_cast(short8, a[kk]), acc[nt]);       \
    }                                                                         \
  }

  for (int t = 0; t < S_LEN; ++t) {
    // ---- T-table prefetch (independent of flags; hides under poll) ----
    float4 t0, t1, t2, t3;
    if (tf != 0) {
      const float* Trow = Tt + (size_t)e_input[t * BATCH + b] * GATES;
      t0 = *(const float4*)(Trow + 0 * HID + hcol);
      t1 = *(const float4*)(Trow + 1 * HID + hcol);
      t2 = *(const float4*)(Trow + 2 * HID + hcol);
      t3 = *(const float4*)(Trow + 3 * HID + hcol);
    }

    // ---- streaming gated burst: lane l polls byte w of block l's word ----
    const unsigned char* fb = (const unsigned char*)(flags + (size_t)t * 64 + l) + w;
    u64 seen = 0;
    bool mine = false;
    int guard = 0;
    auto waitchunk = [&](int c) {
      const u64 m = 0xFFFFull << (16 * c);
      while ((seen & m) != m) {
        if (!mine)
          mine = (__hip_atomic_load(fb, __ATOMIC_RELAXED,
                                    __HIP_MEMORY_SCOPE_AGENT) != 0);
        seen = __ballot(mine);
        if (++guard > (1 << 24)) break;   // safety valve: never hang
      }
    };

    const char* hbl = hbuf + (size_t)(t & 1) * HBUF_BYTES
                      + (((size_t)w * 32 * 64 + l) << 4);   // kk stride 1024B
    i32x4 a[32];
    waitchunk(0); ISSUE(0)
    waitchunk(1); ISSUE(1)
    waitchunk(2); ISSUE(2)
    waitchunk(3); ISSUE(3)
    f32x4 acc[4];
    acc[0] = {0.f, 0.f, 0.f, 0.f}; acc[1] = {0.f, 0.f, 0.f, 0.f};
    acc[2] = {0.f, 0.f, 0.f, 0.f}; acc[3] = {0.f, 0.f, 0.f, 0.f};
    asm volatile("s_waitcnt vmcnt(24)" ::: "memory");
    __builtin_amdgcn_sched_barrier(0);
    MFMA_BT(0)
    asm volatile("s_waitcnt vmcnt(16)" ::: "memory");
    __builtin_amdgcn_sched_barrier(0);
    MFMA_BT(1)
    asm volatile("s_waitcnt vmcnt(8)" ::: "memory");
    __builtin_amdgcn_sched_barrier(0);
    MFMA_BT(2)
    asm volatile("s_waitcnt vmcnt(0)" ::: "memory");
    __builtin_amdgcn_sched_barrier(0);
    MFMA_BT(3)

    // ---- cell update straight from acc registers (no LDS exchange) ----
    float gq[4][4];
#pragma unroll
    for (int g = 0; g < 4; ++g)
#pragma unroll
      for (int r = 0; r < 4; ++r)
        gq[g][r] = acc[g][r];
    if (tf != 0) {
      gq[0][0] += t0.x; gq[0][1] += t0.y; gq[0][2] += t0.z; gq[0][3] += t0.w;
      gq[1][0] += t1.x; gq[1][1] += t1.y; gq[1][2] += t1.z; gq[1][3] += t1.w;
      gq[2][0] += t2.x; gq[2][1] += t2.y; gq[2][2] += t2.z; gq[2][3] += t2.w;
      gq[3][0] += t3.x; gq[3][1] += t3.y; gq[3][2] += t3.z; gq[3][3] += t3.w;
    } else {
      // dense path (unused in this bench, kept for semantic completeness)
      const float* x = d_input + ((size_t)t * BATCH + b) * RDIM;
#pragma unroll
      for (int g = 0; g < 4; ++g)
#pragma unroll
        for (int r = 0; r < 4; ++r) {
          const int row = g * HID + hcol + r;
          const float* wr = W_ih + (size_t)row * RDIM;
          float s = b_ih[row] + b_hh[row];
          for (int k = 0; k < RDIM; ++k) s += x[k] * wr[k];
          gq[g][r] += s;
        }
    }
    float hnew[4];
#pragma unroll
    for (int r = 0; r < 4; ++r) {
      float ig = sigm(gq[0][r]);
      float fg = sigm(gq[1][r]);
      float gg = tanh_(gq[2][r]);
      float og = sigm(gq[3][r]);
      cr[r] = fg * cr[r] + ig * gg;
      hnew[r] = og * tanh_(cr[r]);
    }
    const u64 pk = pack4(hnew[0], hnew[1], hnew[2], hnew[3]);
    // ring store (critical publish path)
    stfrag8(hbuf + (size_t)((t + 1) & 1) * HBUF_BYTES + fragoff(b, hcol), pk);
    if (t == S_LEN - 1) {
      *(float4*)(dout + OFF_H + (size_t)b * HID + hcol) = make_float4(hnew[0], hnew[1], hnew[2], hnew[3]);
      *(float4*)(dout + OFF_C + (size_t)b * HID + hcol) = make_float4(cr[0], cr[1], cr[2], cr[3]);
    }
    // drain THIS WAVE's stores, publish its byte, then outs (off-path)
    asm volatile("s_waitcnt vmcnt(0)" ::: "memory");
    if (l == 0 && t < S_LEN - 1)
      __hip_atomic_store((unsigned char*)(flags + (size_t)(t + 1) * 64 + j) + w,
                         (unsigned char)1,
                         __ATOMIC_RELAXED, __HIP_MEMORY_SCOPE_AGENT);
    *(u64*)(outs_r + (size_t)j * 262144 + ((size_t)t * BATCH + b) * 16 + hcl) = pk;
  }
#undef ISSUE
#undef MFMA_BT
}

// ---------------- projection: logits = outs @ fc_w^T + fc_b ----------------
// grid 2048 x 256, 64x64 tile per block; A is outs_r[j16][t][b][16]
__global__ void __launch_bounds__(256) k_gemm(
    const unsigned short* __restrict__ A,   // outs_r bf16 [64][256][64][16]
    const unsigned short* __restrict__ Bw,  // fc_w bf16 [512][1024]
    const float* __restrict__ fcb, float* __restrict__ C)
{
  const int bid = blockIdx.x;
  const int m0 = (bid >> 3) * 64, n0 = (bid & 7) * 64;
  const int tid = threadIdx.x, w = tid >> 6, l = tid & 63;
  const int mt0 = (w >> 1) * 2, nt0 = (w & 1) * 2;
  f32x4 acc[2][2];
  acc[0][0] = {0.f, 0.f, 0.f, 0.f}; acc[0][1] = {0.f, 0.f, 0.f, 0.f};
  acc[1][0] = {0.f, 0.f, 0.f, 0.f}; acc[1][1] = {0.f, 0.f, 0.f, 0.f};
  const int ksel  = (l >> 4) & 3;           // 0..3 -> k-offset selector
  const int jsel  = ksel >> 1;              // j16 sub-step 0,0,1,1
  const int koffL = (ksel & 1) * 8;         // 0,8,0,8
  const int m_a0 = m0 + mt0 * 16 + (l & 15);
  const unsigned short* a0p = A + (size_t)jsel * 262144 + (size_t)m_a0 * 16 + koffL;
  const unsigned short* a1p = a0p + 16 * 16;   // +16 rows of m -> +256 elems
  const int koff = ksel * 8;
  const unsigned short* b0p = Bw + (size_t)(n0 + nt0 * 16 + (l & 15)) * HID + koff;
  const unsigned short* b1p = b0p + 16 * HID;
#pragma unroll 4
  for (int kk = 0; kk < 32; ++kk) {
    short8 A0 = *(const short8*)(a0p + (size_t)kk * 524288);
    short8 A1 = *(const short8*)(a1p + (size_t)kk * 524288);
    short8 B0 = *(const short8*)(b0p + kk * 32);
    short8 B1 = *(const short8*)(b1p + kk * 32);
    acc[0][0] = mfma16(A0, B0, acc[0][0]);
    acc[0][1] = mfma16(A0, B1, acc[0][1]);
    acc[1][0] = mfma16(A1, B0, acc[1][0]);
    acc[1][1] = mfma16(A1, B1, acc[1][1]);
  }
  const int rb = (l >> 4) * 4, cb = l & 15;
#pragma unroll
  for (int i2 = 0; i2 < 2; ++i2)
#pragma unroll
    for (int j2 = 0; j2 < 2; ++j2) {
      const int n = n0 + (nt0 + j2) * 16 + cb;
      const float fb = fcb[n];
#pragma unroll
      for (int r = 0; r < 4; ++r) {
        const int m = m0 + (mt0 + i2) * 16 + rb + r;
        C[(size_t)m * VOC + n] = acc[i2][j2][r] + fb;
      }
    }
}

// ---------------- loss: -mean(logp[label]) ----------------
// grid 256 x 256 (4 waves x 16 rows each)
__global__ void __launch_bounds__(256) k_loss(
    const float* __restrict__ logits, const int* __restrict__ labels,
    float* __restrict__ dout)
{
  const int tid = threadIdx.x, w = tid >> 6, l = tid & 63;
  float part = 0.f;
  for (int i = 0; i < 16; ++i) {
    const int row = blockIdx.x * 64 + w * 16 + i;
    const float* lr = logits + (size_t)row * VOC;
    float4 x0 = *(const float4*)(lr + l * 8);
    float4 x1 = *(const float4*)(lr + l * 8 + 4);
    float v[8] = {x0.x, x0.y, x0.z, x0.w, x1.x, x1.y, x1.z, x1.w};
    float mx = v[0];
#pragma unroll
    for (int k = 1; k < 8; ++k) mx = fmaxf(mx, v[k]);
    for (int off = 32; off; off >>= 1) mx = fmaxf(mx, __shfl_xor(mx, off));
    float se = 0.f;
#pragma unroll
    for (int k = 0; k < 8; ++k) se += __expf(v[k] - mx);
    for (int off = 32; off; off >>= 1) se += __shfl_xor(se, off);
    const float lse = mx + __logf(se);
    const int lab = labels[row];
    const int li = lab - l * 8;
    float pick = v[0];
#pragma unroll
    for (int k = 1; k < 8; ++k) pick = (li == k) ? v[k] : pick;
    float term = (li >= 0 && li < 8) ? (lse - pick) : 0.f;
    for (int off = 32; off; off >>= 1) term += __shfl_xor(term, off);
    part += term;
  }
  if (l == 0) atomicAdd(dout + OFF_LOSS, part * (1.f / 16384.f));
}

// ---------------- host launch ----------------
extern "C" void kernel_launch(void* const* d_in, const int* in_sizes, int n_in,
                              void* d_out, int out_size, void* d_ws, size_t ws_size,
                              hipStream_t stream) {
  const float* d_input = (const float*)d_in[0];
  const int*   cond    = (const int*)d_in[1];
  const int*   e_input = (const int*)d_in[2];
  const int*   tf_ptr  = (const int*)d_in[3];
  const float* emb     = (const float*)d_in[4];
  const float* W_ih    = (const float*)d_in[5];
  const float* W_hh    = (const float*)d_in[6];
  const float* b_ih    = (const float*)d_in[7];
  const float* b_hh    = (const float*)d_in[8];
  const float* fc_w    = (const float*)d_in[9];
  const float* fc_b    = (const float*)d_in[10];
  float* out = (float*)d_out;
  char*  ws  = (char*)d_ws;

  // ws layout (bytes) — R4/R10-proven
  const size_t WS_T    = 0;                        // 8 MiB fp32 T[512][4096]
  const size_t WS_FCW  = 8388608;                  // 1 MiB bf16 fc_w
  const size_t WS_OUTS = 9437184;                  // 32 MiB bf16 outs_r[64][256][64][16]
  const size_t WS_HBUF = 42991616;                 // h fragment ring (2 x 128 KiB)
  const size_t WS_FLAG = WS_HBUF + 2ull * HBUF_BYTES;  // flags
  char* hbuf = ws + WS_HBUF;
  unsigned* flags = (unsigned*)(ws + WS_FLAG);
  float* T = (float*)(ws + WS_T);
  unsigned short* fcw  = (unsigned short*)(ws + WS_FCW);
  unsigned short* outs = (unsigned short*)(ws + WS_OUTS);

  hipFuncSetAttribute((const void*)k_recur,
                      hipFuncAttributeMaxDynamicSharedMemorySize, 131072);

  k_prep<<<dim3(517), dim3(256), 0, stream>>>(W_ih, b_ih, b_hh, fc_w, T, fcw,
                                              flags, out + OFF_LOSS);
  k_recur<<<dim3(64), dim3(256), 131072, stream>>>(
      W_hh, T, e_input, emb, cond, d_input, tf_ptr, W_ih, b_ih, b_hh,
      hbuf, flags, outs, out);
  k_gemm<<<dim3(2048), dim3(256), 0, stream>>>(outs, fcw, fc_b, out);
  k_loss<<<dim3(256), dim3(256), 0, stream>>>(out, e_input, out);
}

// Round 15
// 2216.349 us; speedup vs baseline: 1.1649x; 1.1649x over previous
//
#include <hip/hip_runtime.h>
#include <hip/hip_bf16.h>
#include <stdint.h>

// Problem constants
#define S_LEN 256
#define BATCH 64
#define HID   1024
#define RDIM  512
#define VOC   512
#define GATES 4096  // 4*HID

// d_out element offsets (fp32): logits [S][B][V], h [1][B][H], c [1][B][H], loss [1]
#define OFF_H    8388608u
#define OFF_C    8454144u
#define OFF_LOSS 8519680u

typedef __attribute__((ext_vector_type(8))) short short8;   // 8 x bf16 (4 VGPR)
typedef __attribute__((ext_vector_type(4))) float f32x4;
typedef __attribute__((ext_vector_type(4))) int   i32x4;
typedef unsigned long long u64;

#define HBUF_BYTES (128u * 1024u)  // one h fragment buffer: 4bt*32kk*64lane*16B

// ---------------- helpers ----------------

__device__ inline unsigned short f2bf(float f) {
  unsigned u = __builtin_bit_cast(unsigned, f);
  return (unsigned short)((u + 0x7FFFu + ((u >> 16) & 1u)) >> 16);
}

__device__ inline u64 pack4(float a, float b, float c, float d) {
  return (u64)f2bf(a) | ((u64)f2bf(b) << 16) | ((u64)f2bf(c) << 32) | ((u64)f2bf(d) << 48);
}

__device__ inline f32x4 mfma16(short8 a, short8 b, f32x4 c) {
  return __builtin_amdgcn_mfma_f32_16x16x32_bf16(a, b, c, 0, 0, 0);
}

__device__ inline void stfrag8(char* p, u64 v) {
  __hip_atomic_store((u64*)p, v, __ATOMIC_RELAXED, __HIP_MEMORY_SCOPE_AGENT);
}

// ring byte offset of h element block (b, hcol..hcol+3), hcol % 4 == 0
// (B-operand fragment layout: lane = (b&15) + k-chunk*16, 8 bf16 per lane entry)
__device__ inline size_t fragoff(int b, int hcol) {
  int bt = b >> 4, kk = hcol >> 5;
  int lane = (b & 15) + (((hcol >> 3) & 3) << 4);
  return ((((size_t)bt * 32 + kk) * 64 + lane) << 4) + (size_t)((hcol & 7) * 2);
}

__device__ inline float sigm(float x) {
  return __builtin_amdgcn_rcpf(1.f + __expf(-x));
}
__device__ inline float tanh_(float x) {
  return 1.f - 2.f * __builtin_amdgcn_rcpf(__expf(2.f * x) + 1.f);
}

// ---------------- prep: T table, fc_w->bf16, zero flags/loss ----------------
// grid 517 x 256
__global__ void __launch_bounds__(256) k_prep(
    const float* __restrict__ W_ih, const float* __restrict__ b_ih,
    const float* __restrict__ b_hh, const float* __restrict__ fc_w,
    float* __restrict__ T, unsigned short* __restrict__ fcw_bf,
    unsigned* __restrict__ flags, float* __restrict__ loss_slot)
{
  __shared__ float stage[64][65];
  const int bid = blockIdx.x, tid = threadIdx.x;
  if (bid < 512) {
    // T[e][c] = W_ih[c][e] + b_ih[c] + b_hh[c]  (64x64 transpose tile)
    const int c0 = (bid >> 3) * 64, e0 = (bid & 7) * 64;
    for (int idx = tid; idx < 4096; idx += 256) {
      int i = idx >> 6, jj = idx & 63;
      stage[i][jj] = W_ih[(size_t)(c0 + i) * RDIM + e0 + jj];
    }
    __syncthreads();
    for (int idx = tid; idx < 4096; idx += 256) {
      int jj = idx >> 6, i = idx & 63;
      int c = c0 + i;
      T[(size_t)(e0 + jj) * GATES + c] = stage[i][jj] + b_ih[c] + b_hh[c];
    }
  } else if (bid < 516) {
    // fc_w fp32 -> bf16
    const size_t off = (size_t)(bid - 512) * 131072;
    for (int k = tid; k < 32768; k += 256) {
      float4 v = *(const float4*)(fc_w + off + (size_t)k * 4);
      ushort4 o;
      o.x = f2bf(v.x); o.y = f2bf(v.y); o.z = f2bf(v.z); o.w = f2bf(v.w);
      *(ushort4*)(fcw_bf + off + (size_t)k * 4) = o;
    }
  } else {
    // zero flags (write-through to LLC) + loss accumulator
    for (int k = tid; k < 65536; k += 256)
      __hip_atomic_store(flags + k, 0u, __ATOMIC_RELAXED, __HIP_MEMORY_SCOPE_AGENT);
    if (tid == 0) loss_slot[0] = 0.f;
  }
}

// ---------------- persistent LSTM recurrence ----------------
// R10 data path (best measured: 1310us) + W amortized over a batch-pair.
// 64 blocks x 2 waves (128 thr). Block j owns gate cols [16j,16j+16) x 4
// gates; W slice (128 KiB) in LDS. Wave w owns batch tiles {2w, 2w+1}: in
// the inner loop each W-fragment is read from LDS ONCE and MFMA'd against
// BOTH tiles' h -> W LDS traffic 512->256 KiB/CU/step (R10's dominant
// term halved), h LLC bytes/block unchanged (128 KiB, no duplication),
// cell inputs still come straight from the wave's own acc registers.
// The two waves share only read-only Wlds => fully independent 64-CU
// recurrence planes over disjoint batch halves: per-wave byte flags in
// one u32/(t,block), simple word-poll of OWN byte, NO in-loop barriers.
// Burst: R10-proven chunk-pipelined shape (16-frag chunks, double-
// buffered, counted vmcnt(16)/(0) drains, 128 asm-pinned VGPRs).
// WAR (2-slot ring, per plane): flags[t][i].byte_w implies block i wave w
// read ALL its slot-(t-1)&1 fragments; the writer polls those flags in
// step t before overwriting that slot for step t+1.
__global__ void __launch_bounds__(128, 1) k_recur(
    const float* __restrict__ W_hh, const float* __restrict__ Tt,
    const int* __restrict__ e_input, const float* __restrict__ emb,
    const int* __restrict__ cond, const float* __restrict__ d_input,
    const int* __restrict__ tf_ptr, const float* __restrict__ W_ih,
    const float* __restrict__ b_ih, const float* __restrict__ b_hh,
    char* __restrict__ hbuf, unsigned* __restrict__ flags,
    unsigned short* __restrict__ outs_r, float* __restrict__ dout)
{
  extern __shared__ char smem[];
  char* Wlds = smem;                         // 128 KiB W fragments (A-operand)
  const int j = blockIdx.x;
  const int tid = threadIdx.x;
  const int w = tid >> 6, l = tid & 63;      // w in {0,1}
  const int tf = tf_ptr[0];

  // ---- pack W_hh slice into LDS fragments (lane = gatecol&15 + kchunk*16) ----
  for (int idx = tid; idx < 8192; idx += 128) {
    const int g = idx >> 11, kk = (idx >> 6) & 31, lane = idx & 63;
    const float* wr = W_hh + (size_t)(g * HID + j * 16 + (lane & 15)) * HID
                      + kk * 32 + ((lane >> 4) & 3) * 8;
    float4 va = *(const float4*)wr;
    float4 vb = *(const float4*)(wr + 4);
    char* p = Wlds + (((size_t)(g * 32 + kk) * 64 + lane) << 4);
    *(u64*)p = pack4(va.x, va.y, va.z, va.w);
    *(u64*)(p + 8) = pack4(vb.x, vb.y, vb.z, vb.w);
  }

  // ---- cell ownership: bts {2w,2w+1}; b0 = 2w*16+(l&15), b1 = b0+16 ----
  const int b0 = (2 * w) * 16 + (l & 15);
  const int b1 = b0 + 16;
  const int hcl = (l >> 4) * 4;
  const int hcol = j * 16 + hcl;
  float cr0[4], cr1[4];
  {
    float4 h0 = *(const float4*)(emb + (size_t)cond[b0] * HID + hcol);
    float4 h1 = *(const float4*)(emb + (size_t)cond[b1] * HID + hcol);
    cr0[0] = h0.x; cr0[1] = h0.y; cr0[2] = h0.z; cr0[3] = h0.w;
    cr1[0] = h1.x; cr1[1] = h1.y; cr1[2] = h1.z; cr1[3] = h1.w;
    stfrag8(hbuf + fragoff(b0, hcol), pack4(h0.x, h0.y, h0.z, h0.w));
    stfrag8(hbuf + fragoff(b1, hcol), pack4(h1.x, h1.y, h1.z, h1.w));
  }
  asm volatile("s_waitcnt vmcnt(0)" ::: "memory");
  if (l == 0)
    __hip_atomic_store((unsigned char*)(flags + j) + w, (unsigned char)1,
                       __ATOMIC_RELAXED, __HIP_MEMORY_SCOPE_AGENT);
  __syncthreads();   // Wlds pack visible to both waves (startup only)

#define ISSUE(buf, c)                                                         \
  _Pragma("unroll")                                                           \
  for (int q = 0; q < 8; ++q)                                                 \
    asm volatile("global_load_dwordx4 %0, %1, off sc0 sc1"                    \
                 : "=v"(buf[q])                                               \
                 : "v"(hbl + (size_t)((c) * 8 + q) * 1024));                  \
  _Pragma("unroll")                                                           \
  for (int q = 0; q < 8; ++q)                                                 \
    asm volatile("global_load_dwordx4 %0, %1, off sc0 sc1"                    \
                 : "=v"(buf[8 + q])                                           \
                 : "v"(hbl + 32768 + (size_t)((c) * 8 + q) * 1024));

#define MFMA_C(c, buf)                                                        \
  _Pragma("unroll")                                                           \
  for (int kkl = 0; kkl < 8; ++kkl) {                                         \
    const int kk = (c) * 8 + kkl;                                             \
    _Pragma("unroll")                                                         \
    for (int nt = 0; nt < 4; ++nt) {                                          \
      short8 Wv = *(const short8*)(Wlds + ((((size_t)nt * 32 + kk) * 64 + l) << 4)); \
      acc0[nt] = mfma16(Wv, __builtin_bit_cast(short8, buf[kkl]), acc0[nt]);  \
      acc1[nt] = mfma16(Wv, __builtin_bit_cast(short8, buf[8 + kkl]), acc1[nt]); \
    }                                                                         \
  }

  for (int t = 0; t < S_LEN; ++t) {
    // ---- T-table prefetch for both bts (independent of flags) ----
    float4 t0, t1, t2, t3, u0, u1, u2, u3;
    if (tf != 0) {
      const float* Trow0 = Tt + (size_t)e_input[t * BATCH + b0] * GATES;
      const float* Trow1 = Tt + (size_t)e_input[t * BATCH + b1] * GATES;
      t0 = *(const float4*)(Trow0 + 0 * HID + hcol);
      t1 = *(const float4*)(Trow0 + 1 * HID + hcol);
      t2 = *(const float4*)(Trow0 + 2 * HID + hcol);
      t3 = *(const float4*)(Trow0 + 3 * HID + hcol);
      u0 = *(const float4*)(Trow1 + 0 * HID + hcol);
      u1 = *(const float4*)(Trow1 + 1 * HID + hcol);
      u2 = *(const float4*)(Trow1 + 2 * HID + hcol);
      u3 = *(const float4*)(Trow1 + 3 * HID + hcol);
    }

    // ---- poll OWN plane's byte of block l's word (no barriers) ----
    {
      const unsigned* fp = flags + (size_t)t * 64 + l;
      int guard = 0;
      while (((__hip_atomic_load(fp, __ATOMIC_RELAXED, __HIP_MEMORY_SCOPE_AGENT)
               >> (8 * w)) & 0xFFu) == 0u) {
        __builtin_amdgcn_s_sleep(1);
        if (++guard > (1 << 24)) break;   // safety valve: never hang
      }
    }

    // ---- h-burst: 4 chunks x 16 frags (bt-pair), double-buffered,
    //      counted vmcnt(16)/(0) drains; W read ONCE per fragment. ----
    const char* hbl = hbuf + (size_t)(t & 1) * HBUF_BYTES
                      + (((size_t)(2 * w) * 32 * 64 + l) << 4);
    i32x4 bufA[16], bufB[16];
    f32x4 acc0[4], acc1[4];
    acc0[0] = {0.f,0.f,0.f,0.f}; acc0[1] = {0.f,0.f,0.f,0.f};
    acc0[2] = {0.f,0.f,0.f,0.f}; acc0[3] = {0.f,0.f,0.f,0.f};
    acc1[0] = {0.f,0.f,0.f,0.f}; acc1[1] = {0.f,0.f,0.f,0.f};
    acc1[2] = {0.f,0.f,0.f,0.f}; acc1[3] = {0.f,0.f,0.f,0.f};
    ISSUE(bufA, 0)
    ISSUE(bufB, 1)
    asm volatile("s_waitcnt vmcnt(16)" ::: "memory");
    __builtin_amdgcn_sched_barrier(0);
    MFMA_C(0, bufA)
    ISSUE(bufA, 2)
    asm volatile("s_waitcnt vmcnt(16)" ::: "memory");
    __builtin_amdgcn_sched_barrier(0);
    MFMA_C(1, bufB)
    ISSUE(bufB, 3)
    asm volatile("s_waitcnt vmcnt(16)" ::: "memory");
    __builtin_amdgcn_sched_barrier(0);
    MFMA_C(2, bufA)
    asm volatile("s_waitcnt vmcnt(0)" ::: "memory");
    __builtin_amdgcn_sched_barrier(0);
    MFMA_C(3, bufB)

    // ---- cell update for both bts straight from acc registers ----
    float gq[4][4];
#pragma unroll
    for (int g = 0; g < 4; ++g)
#pragma unroll
      for (int r = 0; r < 4; ++r)
        gq[g][r] = acc0[g][r];
    if (tf != 0) {
      gq[0][0] += t0.x; gq[0][1] += t0.y; gq[0][2] += t0.z; gq[0][3] += t0.w;
      gq[1][0] += t1.x; gq[1][1] += t1.y; gq[1][2] += t1.z; gq[1][3] += t1.w;
      gq[2][0] += t2.x; gq[2][1] += t2.y; gq[2][2] += t2.z; gq[2][3] += t2.w;
      gq[3][0] += t3.x; gq[3][1] += t3.y; gq[3][2] += t3.z; gq[3][3] += t3.w;
    } else {
      const float* x = d_input + ((size_t)t * BATCH + b0) * RDIM;
#pragma unroll
      for (int g = 0; g < 4; ++g)
#pragma unroll
        for (int r = 0; r < 4; ++r) {
          const int row = g * HID + hcol + r;
          const float* wr = W_ih + (size_t)row * RDIM;
          float s = b_ih[row] + b_hh[row];
          for (int k = 0; k < RDIM; ++k) s += x[k] * wr[k];
          gq[g][r] += s;
        }
    }
    float h0n[4];
#pragma unroll
    for (int r = 0; r < 4; ++r) {
      float ig = sigm(gq[0][r]);
      float fg = sigm(gq[1][r]);
      float gg = tanh_(gq[2][r]);
      float og = sigm(gq[3][r]);
      cr0[r] = fg * cr0[r] + ig * gg;
      h0n[r] = og * tanh_(cr0[r]);
    }
#pragma unroll
    for (int g = 0; g < 4; ++g)
#pragma unroll
      for (int r = 0; r < 4; ++r)
        gq[g][r] = acc1[g][r];
    if (tf != 0) {
      gq[0][0] += u0.x; gq[0][1] += u0.y; gq[0][2] += u0.z; gq[0][3] += u0.w;
      gq[1][0] += u1.x; gq[1][1] += u1.y; gq[1][2] += u1.z; gq[1][3] += u1.w;
      gq[2][0] += u2.x; gq[2][1] += u2.y; gq[2][2] += u2.z; gq[2][3] += u2.w;
      gq[3][0] += u3.x; gq[3][1] += u3.y; gq[3][2] += u3.z; gq[3][3] += u3.w;
    } else {
      const float* x = d_input + ((size_t)t * BATCH + b1) * RDIM;
#pragma unroll
      for (int g = 0; g < 4; ++g)
#pragma unroll
        for (int r = 0; r < 4; ++r) {
          const int row = g * HID + hcol + r;
          const float* wr = W_ih + (size_t)row * RDIM;
          float s = b_ih[row] + b_hh[row];
          for (int k = 0; k < RDIM; ++k) s += x[k] * wr[k];
          gq[g][r] += s;
        }
    }
    float h1n[4];
#pragma unroll
    for (int r = 0; r < 4; ++r) {
      float ig = sigm(gq[0][r]);
      float fg = sigm(gq[1][r]);
      float gg = tanh_(gq[2][r]);
      float og = sigm(gq[3][r]);
      cr1[r] = fg * cr1[r] + ig * gg;
      h1n[r] = og * tanh_(cr1[r]);
    }

    const u64 pk0 = pack4(h0n[0], h0n[1], h0n[2], h0n[3]);
    const u64 pk1 = pack4(h1n[0], h1n[1], h1n[2], h1n[3]);
    // ring stores first (critical publish path)
    char* slot = hbuf + (size_t)((t + 1) & 1) * HBUF_BYTES;
    stfrag8(slot + fragoff(b0, hcol), pk0);
    stfrag8(slot + fragoff(b1, hcol), pk1);
    if (t == S_LEN - 1) {
      *(float4*)(dout + OFF_H + (size_t)b0 * HID + hcol) = make_float4(h0n[0], h0n[1], h0n[2], h0n[3]);
      *(float4*)(dout + OFF_C + (size_t)b0 * HID + hcol) = make_float4(cr0[0], cr0[1], cr0[2], cr0[3]);
      *(float4*)(dout + OFF_H + (size_t)b1 * HID + hcol) = make_float4(h1n[0], h1n[1], h1n[2], h1n[3]);
      *(float4*)(dout + OFF_C + (size_t)b1 * HID + hcol) = make_float4(cr1[0], cr1[1], cr1[2], cr1[3]);
    }
    // drain THIS WAVE's stores, publish its byte; outs after (off-path)
    asm volatile("s_waitcnt vmcnt(0)" ::: "memory");
    if (l == 0 && t < S_LEN - 1)
      __hip_atomic_store((unsigned char*)(flags + (size_t)(t + 1) * 64 + j) + w,
                         (unsigned char)1,
                         __ATOMIC_RELAXED, __HIP_MEMORY_SCOPE_AGENT);
    *(u64*)(outs_r + (size_t)j * 262144 + ((size_t)t * BATCH + b0) * 16 + hcl) = pk0;
    *(u64*)(outs_r + (size_t)j * 262144 + ((size_t)t * BATCH + b1) * 16 + hcl) = pk1;
  }
#undef ISSUE
#undef MFMA_C
}

// ---------------- projection: logits = outs @ fc_w^T + fc_b ----------------
// grid 2048 x 256, 64x64 tile per block; A is outs_r[j16][t][b][16]
__global__ void __launch_bounds__(256) k_gemm(
    const unsigned short* __restrict__ A,   // outs_r bf16 [64][256][64][16]
    const unsigned short* __restrict__ Bw,  // fc_w bf16 [512][1024]
    const float* __restrict__ fcb, float* __restrict__ C)
{
  const int bid = blockIdx.x;
  const int m0 = (bid >> 3) * 64, n0 = (bid & 7) * 64;
  const int tid = threadIdx.x, w = tid >> 6, l = tid & 63;
  const int mt0 = (w >> 1) * 2, nt0 = (w & 1) * 2;
  f32x4 acc[2][2];
  acc[0][0] = {0.f, 0.f, 0.f, 0.f}; acc[0][1] = {0.f, 0.f, 0.f, 0.f};
  acc[1][0] = {0.f, 0.f, 0.f, 0.f}; acc[1][1] = {0.f, 0.f, 0.f, 0.f};
  const int ksel  = (l >> 4) & 3;           // 0..3 -> k-offset selector
  const int jsel  = ksel >> 1;              // j16 sub-step 0,0,1,1
  const int koffL = (ksel & 1) * 8;         // 0,8,0,8
  const int m_a0 = m0 + mt0 * 16 + (l & 15);
  const unsigned short* a0p = A + (size_t)jsel * 262144 + (size_t)m_a0 * 16 + koffL;
  const unsigned short* a1p = a0p + 16 * 16;   // +16 rows of m -> +256 elems
  const int koff = ksel * 8;
  const unsigned short* b0p = Bw + (size_t)(n0 + nt0 * 16 + (l & 15)) * HID + koff;
  const unsigned short* b1p = b0p + 16 * HID;
#pragma unroll 4
  for (int kk = 0; kk < 32; ++kk) {
    short8 A0 = *(const short8*)(a0p + (size_t)kk * 524288);
    short8 A1 = *(const short8*)(a1p + (size_t)kk * 524288);
    short8 B0 = *(const short8*)(b0p + kk * 32);
    short8 B1 = *(const short8*)(b1p + kk * 32);
    acc[0][0] = mfma16(A0, B0, acc[0][0]);
    acc[0][1] = mfma16(A0, B1, acc[0][1]);
    acc[1][0] = mfma16(A1, B0, acc[1][0]);
    acc[1][1] = mfma16(A1, B1, acc[1][1]);
  }
  const int rb = (l >> 4) * 4, cb = l & 15;
#pragma unroll
  for (int i2 = 0; i2 < 2; ++i2)
#pragma unroll
    for (int j2 = 0; j2 < 2; ++j2) {
      const int n = n0 + (nt0 + j2) * 16 + cb;
      const float fb = fcb[n];
#pragma unroll
      for (int r = 0; r < 4; ++r) {
        const int m = m0 + (mt0 + i2) * 16 + rb + r;
        C[(size_t)m * VOC + n] = acc[i2][j2][r] + fb;
      }
    }
}

// ---------------- loss: -mean(logp[label]) ----------------
// grid 256 x 256 (4 waves x 16 rows each)
__global__ void __launch_bounds__(256) k_loss(
    const float* __restrict__ logits, const int* __restrict__ labels,
    float* __restrict__ dout)
{
  const int tid = threadIdx.x, w = tid >> 6, l = tid & 63;
  float part = 0.f;
  for (int i = 0; i < 16; ++i) {
    const int row = blockIdx.x * 64 + w * 16 + i;
    const float* lr = logits + (size_t)row * VOC;
    float4 x0 = *(const float4*)(lr + l * 8);
    float4 x1 = *(const float4*)(lr + l * 8 + 4);
    float v[8] = {x0.x, x0.y, x0.z, x0.w, x1.x, x1.y, x1.z, x1.w};
    float mx = v[0];
#pragma unroll
    for (int k = 1; k < 8; ++k) mx = fmaxf(mx, v[k]);
    for (int off = 32; off; off >>= 1) mx = fmaxf(mx, __shfl_xor(mx, off));
    float se = 0.f;
#pragma unroll
    for (int k = 0; k < 8; ++k) se += __expf(v[k] - mx);
    for (int off = 32; off; off >>= 1) se += __shfl_xor(se, off);
    const float lse = mx + __logf(se);
    const int lab = labels[row];
    const int li = lab - l * 8;
    float pick = v[0];
#pragma unroll
    for (int k = 1; k < 8; ++k) pick = (li == k) ? v[k] : pick;
    float term = (li >= 0 && li < 8) ? (lse - pick) : 0.f;
    for (int off = 32; off; off >>= 1) term += __shfl_xor(term, off);
    part += term;
  }
  if (l == 0) atomicAdd(dout + OFF_LOSS, part * (1.f / 16384.f));
}

// ---------------- host launch ----------------
extern "C" void kernel_launch(void* const* d_in, const int* in_sizes, int n_in,
                              void* d_out, int out_size, void* d_ws, size_t ws_size,
                              hipStream_t stream) {
  const float* d_input = (const float*)d_in[0];
  const int*   cond    = (const int*)d_in[1];
  const int*   e_input = (const int*)d_in[2];
  const int*   tf_ptr  = (const int*)d_in[3];
  const float* emb     = (const float*)d_in[4];
  const float* W_ih    = (const float*)d_in[5];
  const float* W_hh    = (const float*)d_in[6];
  const float* b_ih    = (const float*)d_in[7];
  const float* b_hh    = (const float*)d_in[8];
  const float* fc_w    = (const float*)d_in[9];
  const float* fc_b    = (const float*)d_in[10];
  float* out = (float*)d_out;
  char*  ws  = (char*)d_ws;

  // ws layout (bytes) — R4/R10-proven
  const size_t WS_T    = 0;                        // 8 MiB fp32 T[512][4096]
  const size_t WS_FCW  = 8388608;                  // 1 MiB bf16 fc_w
  const size_t WS_OUTS = 9437184;                  // 32 MiB bf16 outs_r[64][256][64][16]
  const size_t WS_HBUF = 42991616;                 // h fragment ring (2 x 128 KiB)
  const size_t WS_FLAG = WS_HBUF + 2ull * HBUF_BYTES;  // flags
  char* hbuf = ws + WS_HBUF;
  unsigned* flags = (unsigned*)(ws + WS_FLAG);
  float* T = (float*)(ws + WS_T);
  unsigned short* fcw  = (unsigned short*)(ws + WS_FCW);
  unsigned short* outs = (unsigned short*)(ws + WS_OUTS);

  hipFuncSetAttribute((const void*)k_recur,
                      hipFuncAttributeMaxDynamicSharedMemorySize, 131072);

  k_prep<<<dim3(517), dim3(256), 0, stream>>>(W_ih, b_ih, b_hh, fc_w, T, fcw,
                                              flags, out + OFF_LOSS);
  k_recur<<<dim3(64), dim3(128), 131072, stream>>>(
      W_hh, T, e_input, emb, cond, d_input, tf_ptr, W_ih, b_ih, b_hh,
      hbuf, flags, outs, out);
  k_gemm<<<dim3(2048), dim3(256), 0, stream>>>(outs, fcw, fc_b, out);
  k_loss<<<dim3(256), dim3(256), 0, stream>>>(out, e_input, out);
}

// Round 16
// 1424.564 us; speedup vs baseline: 1.8123x; 1.5558x over previous
//
#include <hip/hip_runtime.h>
#include <hip/hip_bf16.h>
#include <stdint.h>

// Problem constants
#define S_LEN 256
#define BATCH 64
#define HID   1024
#define RDIM  512
#define VOC   512
#define GATES 4096  // 4*HID

// d_out element offsets (fp32): logits [S][B][V], h [1][B][H], c [1][B][H], loss [1]
#define OFF_H    8388608u
#define OFF_C    8454144u
#define OFF_LOSS 8519680u

typedef __attribute__((ext_vector_type(8))) short short8;   // 8 x bf16 (4 VGPR)
typedef __attribute__((ext_vector_type(4))) float f32x4;
typedef __attribute__((ext_vector_type(4))) int   i32x4;
typedef unsigned long long u64;

#define HBUF_BYTES (128u * 1024u)  // one h fragment buffer: 4bt*32kk*64lane*16B

// ---------------- helpers ----------------

__device__ inline unsigned short f2bf(float f) {
  unsigned u = __builtin_bit_cast(unsigned, f);
  return (unsigned short)((u + 0x7FFFu + ((u >> 16) & 1u)) >> 16);
}

__device__ inline u64 pack4(float a, float b, float c, float d) {
  return (u64)f2bf(a) | ((u64)f2bf(b) << 16) | ((u64)f2bf(c) << 32) | ((u64)f2bf(d) << 48);
}

__device__ inline f32x4 mfma16(short8 a, short8 b, f32x4 c) {
  return __builtin_amdgcn_mfma_f32_16x16x32_bf16(a, b, c, 0, 0, 0);
}

__device__ inline void stfrag8(char* p, u64 v) {
  __hip_atomic_store((u64*)p, v, __ATOMIC_RELAXED, __HIP_MEMORY_SCOPE_AGENT);
}

// ring byte offset of h element block (b, hcol..hcol+3), hcol % 4 == 0
// (B-operand fragment layout: lane = (b&15) + k-chunk*16, 8 bf16 per lane entry)
__device__ inline size_t fragoff(int b, int hcol) {
  int bt = b >> 4, kk = hcol >> 5;
  int lane = (b & 15) + (((hcol >> 3) & 3) << 4);
  return ((((size_t)bt * 32 + kk) * 64 + lane) << 4) + (size_t)((hcol & 7) * 2);
}

__device__ inline float sigm(float x) {
  return __builtin_amdgcn_rcpf(1.f + __expf(-x));
}
__device__ inline float tanh_(float x) {
  return 1.f - 2.f * __builtin_amdgcn_rcpf(__expf(2.f * x) + 1.f);
}

// ---------------- prep: T table, fc_w->bf16, zero flags/loss ----------------
// grid 517 x 256
__global__ void __launch_bounds__(256) k_prep(
    const float* __restrict__ W_ih, const float* __restrict__ b_ih,
    const float* __restrict__ b_hh, const float* __restrict__ fc_w,
    float* __restrict__ T, unsigned short* __restrict__ fcw_bf,
    unsigned* __restrict__ flags, float* __restrict__ loss_slot)
{
  __shared__ float stage[64][65];
  const int bid = blockIdx.x, tid = threadIdx.x;
  if (bid < 512) {
    // T[e][c] = W_ih[c][e] + b_ih[c] + b_hh[c]  (64x64 transpose tile)
    const int c0 = (bid >> 3) * 64, e0 = (bid & 7) * 64;
    for (int idx = tid; idx < 4096; idx += 256) {
      int i = idx >> 6, jj = idx & 63;
      stage[i][jj] = W_ih[(size_t)(c0 + i) * RDIM + e0 + jj];
    }
    __syncthreads();
    for (int idx = tid; idx < 4096; idx += 256) {
      int jj = idx >> 6, i = idx & 63;
      int c = c0 + i;
      T[(size_t)(e0 + jj) * GATES + c] = stage[i][jj] + b_ih[c] + b_hh[c];
    }
  } else if (bid < 516) {
    // fc_w fp32 -> bf16
    const size_t off = (size_t)(bid - 512) * 131072;
    for (int k = tid; k < 32768; k += 256) {
      float4 v = *(const float4*)(fc_w + off + (size_t)k * 4);
      ushort4 o;
      o.x = f2bf(v.x); o.y = f2bf(v.y); o.z = f2bf(v.z); o.w = f2bf(v.w);
      *(ushort4*)(fcw_bf + off + (size_t)k * 4) = o;
    }
  } else {
    // zero flags (write-through to LLC) + loss accumulator
    for (int k = tid; k < 65536; k += 256)
      __hip_atomic_store(flags + k, 0u, __ATOMIC_RELAXED, __HIP_MEMORY_SCOPE_AGENT);
    if (tid == 0) loss_slot[0] = 0.f;
  }
}

// ---------------- persistent LSTM recurrence ----------------
// Best-measured structure (R10: 1310us k_recur). 64 blocks x 4 waves, 1
// block/CU. Block j owns gate cols [16j,16j+16) x 4 gates; W slice lives in
// LDS as 16x16x32 fragments (packed once). Wave w owns batch tile bt=w. Per
// step: 32-frag asm burst of h (B-operand) from the LLC ring with counted
// vmcnt(24/16/8/0) drains; MFMA with A = W (from LDS), B = h  =>  C
// fragment: row=(l>>4)*4+r = gatecol, col=l&15 = batch. With cell mapping
// b = w*16+(l&15), hcl = (l>>4)*4 each thread's cell inputs are ITS OWN acc
// registers -- no gate exchange at all. Sync: block flags, 64 pollers + 2
// __syncthreads per step. Residual cost is the chip-wide all-to-all LLC
// rendezvous x 256 sequential steps (latency-structural; see session log).
__global__ void __launch_bounds__(256, 1) k_recur(
    const float* __restrict__ W_hh, const float* __restrict__ Tt,
    const int* __restrict__ e_input, const float* __restrict__ emb,
    const int* __restrict__ cond, const float* __restrict__ d_input,
    const int* __restrict__ tf_ptr, const float* __restrict__ W_ih,
    const float* __restrict__ b_ih, const float* __restrict__ b_hh,
    char* __restrict__ hbuf, unsigned* __restrict__ flags,
    unsigned short* __restrict__ outs_r, float* __restrict__ dout)
{
  extern __shared__ char smem[];
  char* Wlds = smem;                         // 128 KiB W fragments (A-operand)
  const int j = blockIdx.x;
  const int tid = threadIdx.x;
  const int w = tid >> 6, l = tid & 63;
  const int tf = tf_ptr[0];

  // ---- pack W_hh slice into LDS fragments (lane = gatecol&15 + kchunk*16) ----
  {
    const int nl = tid >> 2;        // local gate col 0..63 (gate = nl>>4)
    const int kq = tid & 3;
    const int g = nl >> 4, hc = nl & 15;
    const float* wrow = W_hh + (size_t)(g * HID + j * 16 + hc) * HID + kq * 256;
    for (int k8 = 0; k8 < 32; ++k8) {
      const int k = kq * 256 + k8 * 8;
      float4 va = *(const float4*)(wrow + k8 * 8);
      float4 vb = *(const float4*)(wrow + k8 * 8 + 4);
      u64 lo = pack4(va.x, va.y, va.z, va.w);
      u64 hi = pack4(vb.x, vb.y, vb.z, vb.w);
      const int kk = k >> 5;
      const int lane = (nl & 15) + (((k >> 3) & 3) << 4);
      char* p = Wlds + (((size_t)(g * 32 + kk) * 64 + lane) << 4);
      *(u64*)p = lo;
      *(u64*)(p + 8) = hi;
    }
  }

  // ---- cell ownership: b = w*16 + (l&15), hcl = (l>>4)*4 (matches C frag) ----
  const int b = w * 16 + (l & 15);
  const int hcl = (l >> 4) * 4;
  const int hcol = j * 16 + hcl;
  float cr[4];
  {
    const int cd = cond[b];
    float4 h0 = *(const float4*)(emb + (size_t)cd * HID + hcol);
    cr[0] = h0.x; cr[1] = h0.y; cr[2] = h0.z; cr[3] = h0.w;
    stfrag8(hbuf + fragoff(b, hcol), pack4(h0.x, h0.y, h0.z, h0.w));
  }
  asm volatile("s_waitcnt vmcnt(0)" ::: "memory");
  __syncthreads();   // h0 stores drained by all waves; Wlds pack complete
  if (tid == 0)
    __hip_atomic_store(flags + j, 1u, __ATOMIC_RELAXED, __HIP_MEMORY_SCOPE_AGENT);

#define MFMA_BT(bt)                                                           \
  _Pragma("unroll")                                                           \
  for (int kkl = 0; kkl < 8; ++kkl) {                                         \
    const int kk = (bt) * 8 + kkl;                                            \
    _Pragma("unroll")                                                         \
    for (int nt = 0; nt < 4; ++nt) {                                          \
      short8 Wv = *(const short8*)(Wlds + ((((size_t)nt * 32 + kk) * 64 + l) << 4)); \
      acc[nt] = mfma16(Wv, __builtin_bit_cast(short8, a[kk]), acc[nt]);       \
    }                                                                         \
  }

  for (int t = 0; t < S_LEN; ++t) {
    // ---- T-table prefetch (independent of flags; hides under poll) ----
    float4 t0, t1, t2, t3;
    if (tf != 0) {
      const float* Trow = Tt + (size_t)e_input[t * BATCH + b] * GATES;
      t0 = *(const float4*)(Trow + 0 * HID + hcol);
      t1 = *(const float4*)(Trow + 1 * HID + hcol);
      t2 = *(const float4*)(Trow + 2 * HID + hcol);
      t3 = *(const float4*)(Trow + 3 * HID + hcol);
    }

    // ---- wait for every block to publish h^t (64 pollers) ----
    if (tid < 64) {
      const unsigned* fp = flags + (size_t)t * 64 + tid;
      int guard = 0;
      while (__hip_atomic_load(fp, __ATOMIC_RELAXED, __HIP_MEMORY_SCOPE_AGENT) == 0u) {
        __builtin_amdgcn_s_sleep(1);
        if (++guard > (1 << 24)) break;   // safety valve: never hang
      }
    }
    __syncthreads();

    // ---- h-fragment BURST: 32 x global_load_dwordx4 sc0 sc1 in flight,
    //      counted drains. bt = w (wave-unique batch tile). ----
    const char* hbl = hbuf + (size_t)(t & 1) * HBUF_BYTES
                      + (((size_t)w * 32 * 64 + l) << 4);   // kk stride 1024B
    i32x4 a[32];
#pragma unroll
    for (int kk = 0; kk < 32; ++kk) {
      asm volatile("global_load_dwordx4 %0, %1, off sc0 sc1"
                   : "=v"(a[kk]) : "v"(hbl + (size_t)kk * 1024));
    }
    f32x4 acc[4];
    acc[0] = {0.f, 0.f, 0.f, 0.f}; acc[1] = {0.f, 0.f, 0.f, 0.f};
    acc[2] = {0.f, 0.f, 0.f, 0.f}; acc[3] = {0.f, 0.f, 0.f, 0.f};
    asm volatile("s_waitcnt vmcnt(24)" ::: "memory");
    __builtin_amdgcn_sched_barrier(0);
    MFMA_BT(0)
    asm volatile("s_waitcnt vmcnt(16)" ::: "memory");
    __builtin_amdgcn_sched_barrier(0);
    MFMA_BT(1)
    asm volatile("s_waitcnt vmcnt(8)" ::: "memory");
    __builtin_amdgcn_sched_barrier(0);
    MFMA_BT(2)
    asm volatile("s_waitcnt vmcnt(0)" ::: "memory");
    __builtin_amdgcn_sched_barrier(0);
    MFMA_BT(3)

    // ---- cell update straight from acc registers (no LDS exchange) ----
    float gq[4][4];
#pragma unroll
    for (int g = 0; g < 4; ++g)
#pragma unroll
      for (int r = 0; r < 4; ++r)
        gq[g][r] = acc[g][r];
    if (tf != 0) {
      gq[0][0] += t0.x; gq[0][1] += t0.y; gq[0][2] += t0.z; gq[0][3] += t0.w;
      gq[1][0] += t1.x; gq[1][1] += t1.y; gq[1][2] += t1.z; gq[1][3] += t1.w;
      gq[2][0] += t2.x; gq[2][1] += t2.y; gq[2][2] += t2.z; gq[2][3] += t2.w;
      gq[3][0] += t3.x; gq[3][1] += t3.y; gq[3][2] += t3.z; gq[3][3] += t3.w;
    } else {
      // dense path (unused in this bench, kept for semantic completeness)
      const float* x = d_input + ((size_t)t * BATCH + b) * RDIM;
#pragma unroll
      for (int g = 0; g < 4; ++g)
#pragma unroll
        for (int r = 0; r < 4; ++r) {
          const int row = g * HID + hcol + r;
          const float* wr = W_ih + (size_t)row * RDIM;
          float s = b_ih[row] + b_hh[row];
          for (int k = 0; k < RDIM; ++k) s += x[k] * wr[k];
          gq[g][r] += s;
        }
    }
    float hnew[4];
#pragma unroll
    for (int r = 0; r < 4; ++r) {
      float ig = sigm(gq[0][r]);
      float fg = sigm(gq[1][r]);
      float gg = tanh_(gq[2][r]);
      float og = sigm(gq[3][r]);
      cr[r] = fg * cr[r] + ig * gg;
      hnew[r] = og * tanh_(cr[r]);
    }
    const u64 pk = pack4(hnew[0], hnew[1], hnew[2], hnew[3]);
    // ring store first (critical publish path), then outs/dout
    stfrag8(hbuf + (size_t)((t + 1) & 1) * HBUF_BYTES + fragoff(b, hcol), pk);
    *(u64*)(outs_r + (size_t)j * 262144 + ((size_t)t * BATCH + b) * 16 + hcl) = pk;
    if (t == S_LEN - 1) {
      *(float4*)(dout + OFF_H + (size_t)b * HID + hcol) = make_float4(hnew[0], hnew[1], hnew[2], hnew[3]);
      *(float4*)(dout + OFF_C + (size_t)b * HID + hcol) = make_float4(cr[0], cr[1], cr[2], cr[3]);
    }
    // drain all waves' stores, then publish h^{t+1}
    asm volatile("s_waitcnt vmcnt(0)" ::: "memory");
    __syncthreads();
    if (tid == 0 && t < S_LEN - 1)
      __hip_atomic_store(flags + (size_t)(t + 1) * 64 + j, 1u,
                         __ATOMIC_RELAXED, __HIP_MEMORY_SCOPE_AGENT);
  }
#undef MFMA_BT
}

// ---------------- projection: logits = outs @ fc_w^T + fc_b ----------------
// grid 2048 x 256, 64x64 tile per block; A is outs_r[j16][t][b][16]
__global__ void __launch_bounds__(256) k_gemm(
    const unsigned short* __restrict__ A,   // outs_r bf16 [64][256][64][16]
    const unsigned short* __restrict__ Bw,  // fc_w bf16 [512][1024]
    const float* __restrict__ fcb, float* __restrict__ C)
{
  const int bid = blockIdx.x;
  const int m0 = (bid >> 3) * 64, n0 = (bid & 7) * 64;
  const int tid = threadIdx.x, w = tid >> 6, l = tid & 63;
  const int mt0 = (w >> 1) * 2, nt0 = (w & 1) * 2;
  f32x4 acc[2][2];
  acc[0][0] = {0.f, 0.f, 0.f, 0.f}; acc[0][1] = {0.f, 0.f, 0.f, 0.f};
  acc[1][0] = {0.f, 0.f, 0.f, 0.f}; acc[1][1] = {0.f, 0.f, 0.f, 0.f};
  const int ksel  = (l >> 4) & 3;           // 0..3 -> k-offset selector
  const int jsel  = ksel >> 1;              // j16 sub-step 0,0,1,1
  const int koffL = (ksel & 1) * 8;         // 0,8,0,8
  const int m_a0 = m0 + mt0 * 16 + (l & 15);
  const unsigned short* a0p = A + (size_t)jsel * 262144 + (size_t)m_a0 * 16 + koffL;
  const unsigned short* a1p = a0p + 16 * 16;   // +16 rows of m -> +256 elems
  const int koff = ksel * 8;
  const unsigned short* b0p = Bw + (size_t)(n0 + nt0 * 16 + (l & 15)) * HID + koff;
  const unsigned short* b1p = b0p + 16 * HID;
#pragma unroll 4
  for (int kk = 0; kk < 32; ++kk) {
    short8 A0 = *(const short8*)(a0p + (size_t)kk * 524288);
    short8 A1 = *(const short8*)(a1p + (size_t)kk * 524288);
    short8 B0 = *(const short8*)(b0p + kk * 32);
    short8 B1 = *(const short8*)(b1p + kk * 32);
    acc[0][0] = mfma16(A0, B0, acc[0][0]);
    acc[0][1] = mfma16(A0, B1, acc[0][1]);
    acc[1][0] = mfma16(A1, B0, acc[1][0]);
    acc[1][1] = mfma16(A1, B1, acc[1][1]);
  }
  const int rb = (l >> 4) * 4, cb = l & 15;
#pragma unroll
  for (int i2 = 0; i2 < 2; ++i2)
#pragma unroll
    for (int j2 = 0; j2 < 2; ++j2) {
      const int n = n0 + (nt0 + j2) * 16 + cb;
      const float fb = fcb[n];
#pragma unroll
      for (int r = 0; r < 4; ++r) {
        const int m = m0 + (mt0 + i2) * 16 + rb + r;
        C[(size_t)m * VOC + n] = acc[i2][j2][r] + fb;
      }
    }
}

// ---------------- loss: -mean(logp[label]) ----------------
// grid 256 x 256 (4 waves x 16 rows each)
__global__ void __launch_bounds__(256) k_loss(
    const float* __restrict__ logits, const int* __restrict__ labels,
    float* __restrict__ dout)
{
  const int tid = threadIdx.x, w = tid >> 6, l = tid & 63;
  float part = 0.f;
  for (int i = 0; i < 16; ++i) {
    const int row = blockIdx.x * 64 + w * 16 + i;
    const float* lr = logits + (size_t)row * VOC;
    float4 x0 = *(const float4*)(lr + l * 8);
    float4 x1 = *(const float4*)(lr + l * 8 + 4);
    float v[8] = {x0.x, x0.y, x0.z, x0.w, x1.x, x1.y, x1.z, x1.w};
    float mx = v[0];
#pragma unroll
    for (int k = 1; k < 8; ++k) mx = fmaxf(mx, v[k]);
    for (int off = 32; off; off >>= 1) mx = fmaxf(mx, __shfl_xor(mx, off));
    float se = 0.f;
#pragma unroll
    for (int k = 0; k < 8; ++k) se += __expf(v[k] - mx);
    for (int off = 32; off; off >>= 1) se += __shfl_xor(se, off);
    const float lse = mx + __logf(se);
    const int lab = labels[row];
    const int li = lab - l * 8;
    float pick = v[0];
#pragma unroll
    for (int k = 1; k < 8; ++k) pick = (li == k) ? v[k] : pick;
    float term = (li >= 0 && li < 8) ? (lse - pick) : 0.f;
    for (int off = 32; off; off >>= 1) term += __shfl_xor(term, off);
    part += term;
  }
  if (l == 0) atomicAdd(dout + OFF_LOSS, part * (1.f / 16384.f));
}

// ---------------- host launch ----------------
extern "C" void kernel_launch(void* const* d_in, const int* in_sizes, int n_in,
                              void* d_out, int out_size, void* d_ws, size_t ws_size,
                              hipStream_t stream) {
  const float* d_input = (const float*)d_in[0];
  const int*   cond    = (const int*)d_in[1];
  const int*   e_input = (const int*)d_in[2];
  const int*   tf_ptr  = (const int*)d_in[3];
  const float* emb     = (const float*)d_in[4];
  const float* W_ih    = (const float*)d_in[5];
  const float* W_hh    = (const float*)d_in[6];
  const float* b_ih    = (const float*)d_in[7];
  const float* b_hh    = (const float*)d_in[8];
  const float* fc_w    = (const float*)d_in[9];
  const float* fc_b    = (const float*)d_in[10];
  float* out = (float*)d_out;
  char*  ws  = (char*)d_ws;

  // ws layout (bytes) — R4/R10-proven
  const size_t WS_T    = 0;                        // 8 MiB fp32 T[512][4096]
  const size_t WS_FCW  = 8388608;                  // 1 MiB bf16 fc_w
  const size_t WS_OUTS = 9437184;                  // 32 MiB bf16 outs_r[64][256][64][16]
  const size_t WS_HBUF = 42991616;                 // h fragment ring (2 x 128 KiB)
  const size_t WS_FLAG = WS_HBUF + 2ull * HBUF_BYTES;  // flags
  char* hbuf = ws + WS_HBUF;
  unsigned* flags = (unsigned*)(ws + WS_FLAG);
  float* T = (float*)(ws + WS_T);
  unsigned short* fcw  = (unsigned short*)(ws + WS_FCW);
  unsigned short* outs = (unsigned short*)(ws + WS_OUTS);

  hipFuncSetAttribute((const void*)k_recur,
                      hipFuncAttributeMaxDynamicSharedMemorySize, 131072);

  k_prep<<<dim3(517), dim3(256), 0, stream>>>(W_ih, b_ih, b_hh, fc_w, T, fcw,
                                              flags, out + OFF_LOSS);
  k_recur<<<dim3(64), dim3(256), 131072, stream>>>(
      W_hh, T, e_input, emb, cond, d_input, tf_ptr, W_ih, b_ih, b_hh,
      hbuf, flags, outs, out);
  k_gemm<<<dim3(2048), dim3(256), 0, stream>>>(outs, fcw, fc_b, out);
  k_loss<<<dim3(256), dim3(256), 0, stream>>>(out, e_input, out);
}